// Round 13
// baseline (34.573 us; speedup 1.0000x reference)
//
#include <hip/hip_runtime.h>
#include <hip/hip_fp16.h>
#include <math.h>
#include <stdint.h>

#define D_DIM 256
#define K_BINS 32
#define NCELL 1024           // cell 0.00586 < min bin 0.006 -> <=1 boundary/cell
#define ENT4_STRIDE 132      // dwords per dim per half-entry array (32*4 + 4 pad)
#define LIC_STRIDE 34        // floats per dim (33 used + 1 pad)
#define LUT_BSTRIDE 1028     // bytes per dim (1024 + 4 pad)
#define CB_STRIDE 34         // u16 per dim (32 used + 2 pad)
#define SLICE 16             // dims per block

static constexpr float BOUND = 3.0f;
static constexpr float MIN_BIN_W = 1e-3f;
static constexpr float MIN_DERIV = 1e-3f;
static constexpr float MIN_LAMBDA = 0.025f;
static constexpr float EPS_ = 1e-6f;
static constexpr float CELL_W = 6.0f / NCELL;
static constexpr float CELL_S = NCELL / 6.0f;
static constexpr float LN2_ = 0.69314718055994531f;

__device__ __forceinline__ float softplusf_(float x) {
  return fmaxf(x, 0.0f) + log1pf(expf(-fabsf(x)));
}

__device__ __forceinline__ float pack2h_as_f32(float a, float b) {
  __half2 h = __halves2half2(__float2half_rn(a), __float2half_rn(b));
  union { __half2 h; uint32_t u; } c;
  c.h = h;
  return __uint_as_float(c.u);
}

__device__ __forceinline__ float2 unpack2h_from_f32(float v) {
  union { uint32_t u; __half2 h; } c;
  c.u = __float_as_uint(v);
  return make_float2(__low2float(c.h), __high2float(c.h));
}

// butterfly sum within each 4-lane quad via DPP quad_perm (VALU pipe)
__device__ __forceinline__ float dpp_quadsum4(float v) {
  int t;
  t = __builtin_amdgcn_update_dpp(0, __float_as_int(v), 0xB1, 0xF, 0xF, false); // xor1
  v += __int_as_float(t);
  t = __builtin_amdgcn_update_dpp(0, __float_as_int(v), 0x4E, 0xF, 0xF, false); // xor2
  v += __int_as_float(t);
  return v;
}

// one spline eval for local dim `dml` (0..15) from split LDS tables
__device__ __forceinline__ void eval1(
    float xv, int dml,
    const float* lentA, const float* lentB,
    const float* lic, const uint8_t* lutb,
    float& uu_out, float& lad2_out) {
  float xc = fminf(fmaxf(xv, -BOUND), BOUND);
  bool inside = fabsf(xv) <= BOUND;

  float cf = fmaf(xc, CELL_S, (float)(NCELL / 2));
  int c = (int)cf;
  c = min(c, NCELL - 1);
  int ilut = (int)lutb[dml * LUT_BSTRIDE + c];

  float c1 = lic[dml * LIC_STRIDE + ilut + 1];
  int idx = ilut + (xc >= c1 ? 1 : 0);

  int eb = dml * ENT4_STRIDE + idx * 4;
  float4 A = *reinterpret_cast<const float4*>(&lentA[eb]);  // icw,inv_iw,il,wc
  float4 Bv = *reinterpret_cast<const float4*>(&lentB[eb]); // wb,yc,dycdyb,LL

  float icw = A.x, inv_iw = A.y, il = A.z, wcv = A.w;
  float wbv = Bv.x, yc = Bv.y;
  float2 dd = unpack2h_from_f32(Bv.z);   // dyc, dyb
  float2 LL = unpack2h_from_f32(Bv.w);   // Llo, Lhi

  float theta = (xc - icw) * inv_iw;
  bool lo = theta <= il;
  float t1 = il - theta;
  float t3 = 1.0f - theta;

  float den = lo ? fmaf(wcv, theta, t1)
                 : fmaf(wcv, t3, -(wbv * t1));
  float sfac = lo ? dd.x : (wbv * dd.y);
  float Ls = lo ? LL.x : LL.y;

  float r = __builtin_amdgcn_rcpf(den);
  float uu = fmaf(-t1 * sfac, r, yc);
  float lad2 = fmaf(-2.0f, __builtin_amdgcn_logf(den), Ls);  // log2 units

  uu_out = inside ? uu : xv;
  lad2_out = inside ? lad2 : 0.0f;
}

// Fused: 1024 blocks x 512 threads (8 waves). Block owns 16 dims (slice=blk&15),
// builds its own LDS table (cooperative, divergence-free LUT fill), then
// evaluates 4 dims/lane via float4 I/O.
__global__ __launch_bounds__(512) void spline_fused(
    const float* __restrict__ x,
    const float* __restrict__ uw,
    const float* __restrict__ uh,
    const float* __restrict__ ud,
    const float* __restrict__ ul,
    float* __restrict__ uout,
    float* __restrict__ part,
    int B) {
  __shared__ __align__(16) float lentA[SLICE * ENT4_STRIDE];  // 8448 B
  __shared__ __align__(16) float lentB[SLICE * ENT4_STRIDE];  // 8448 B
  __shared__ float lic[SLICE * LIC_STRIDE];                   // 2176 B
  __shared__ uint8_t lutb[SLICE * LUT_BSTRIDE];               // 16448 B
  __shared__ uint16_t cb16[SLICE * CB_STRIDE];                // 1088 B

  int tid = threadIdx.x;
  int slice = blockIdx.x & 15;
  int group = blockIdx.x >> 4;   // 0..63
  int d0 = slice * SLICE;

  // ---------------- build phase ----------------
  {
    int k = tid & 31;
    int dim = tid >> 5;          // 0..15
    int d = d0 + dim;

    float uwv = uw[d * K_BINS + k];
    float uhv = uh[d * K_BINS + k];
    float ulv = ul[d * K_BINS + k];
    float udv = (k < K_BINS - 1) ? ud[d * (K_BINS - 1) + k] : 0.0f;

    float wm = uwv, hm = uhv;
    for (int o = 16; o; o >>= 1) {
      wm = fmaxf(wm, __shfl_xor(wm, o, 32));
      hm = fmaxf(hm, __shfl_xor(hm, o, 32));
    }
    float ew = expf(uwv - wm), eh = expf(uhv - hm);
    float ws = ew, hs = eh;
    for (int o = 16; o; o >>= 1) {
      ws += __shfl_xor(ws, o, 32);
      hs += __shfl_xor(hs, o, 32);
    }
    const float kfac = 1.0f - MIN_BIN_W * (float)K_BINS;
    float sw = MIN_BIN_W + kfac * (ew / ws);
    float sh = MIN_BIN_W + kfac * (eh / hs);

    float cws = sw, chs = sh;
    for (int o = 1; o < 32; o <<= 1) {
      float tw = __shfl_up(cws, o, 32);
      float th = __shfl_up(chs, o, 32);
      if (k >= o) { cws += tw; chs += th; }
    }
    const float scale = 2.0f * BOUND;
    float raw_w = scale * cws - BOUND;
    float raw_h = scale * chs - BOUND;
    float upw = __shfl_up(raw_w, 1, 32);
    float uph = __shfl_up(raw_h, 1, 32);
    float cw_lo = (k == 0) ? -BOUND : upw;
    float ch_lo = (k == 0) ? -BOUND : uph;
    float cw_hi = (k == K_BINS - 1) ? BOUND : raw_w;
    float ch_hi = (k == K_BINS - 1) ? BOUND : raw_h;

    float iw = cw_hi - cw_lo;
    float ih = ch_hi - ch_lo;

    float dk = MIN_DERIV + softplusf_(udv);
    float dprev = __shfl_up(dk, 1, 32);
    float d1 = (k == K_BINS - 1) ? 1.0f : dk;
    float dd0 = (k == 0) ? 1.0f : dprev;

    float sg = 1.0f / (1.0f + expf(-ulv));
    float lam = MIN_LAMBDA + (1.0f - 2.0f * MIN_LAMBDA) * sg;

    float wb = sqrtf(dd0 / d1);
    float delta = ih / iw;
    float wc = (lam * dd0 + (1.0f - lam) * wb * d1) / delta;
    float denom = (1.0f - lam) + lam * wb;
    float dyc = lam * wb * ih / denom;   // yc - ya
    float dyb = ih - dyc;                // yb - yc
    float ya = ch_lo;
    float inv_iw = 1.0f / iw;
    float yc = ya + dyc;

    float* eA = &lentA[dim * ENT4_STRIDE + k * 4];
    eA[0] = cw_lo;
    eA[1] = inv_iw;
    eA[2] = lam;
    eA[3] = wc;
    float* eB = &lentB[dim * ENT4_STRIDE + k * 4];
    eB[0] = wb;
    eB[1] = yc;
    eB[2] = pack2h_as_f32(dyc, dyb);
    eB[3] = pack2h_as_f32(log2f(wc * lam * dyc * inv_iw),
                          log2f(wc * wb * (1.0f - lam) * dyb * inv_iw));

    float t = cw_lo + EPS_;
    lic[dim * LIC_STRIDE + k] = t;
    if (k == 0) lic[dim * LIC_STRIDE + 32] = 1e30f;  // sentinel

    // exact c0 = min{c : cellL(c) >= t}, cellL(c) = fma(c,CELL_W,-3) - 1e-5
    int c0 = 0;
    if (k > 0) {
      float q = (t + BOUND + 1e-5f) * CELL_S;
      c0 = (int)ceilf(q);
      if (c0 < 0) c0 = 0;
      if (c0 > NCELL) c0 = NCELL;
      while (c0 < NCELL && (fmaf((float)c0, CELL_W, -BOUND) - 1e-5f) < t) ++c0;
      while (c0 > 0 && (fmaf((float)(c0 - 1), CELL_W, -BOUND) - 1e-5f) >= t) --c0;
    }
    cb16[dim * CB_STRIDE + k] = (uint16_t)c0;
  }
  __syncthreads();

  // cooperative LUT fill: thread (dim, k) fills cells [32k, 32k+32) of dim.
  // lut[c] = largest j with cb16[j] <= c  (== old per-cell binary search).
  {
    int k = tid & 31;
    int dim = tid >> 5;
    const uint16_t* cb = &cb16[dim * CB_STRIDE];
    int target = k * 32;
    int b = 0;
#pragma unroll
    for (int st = 16; st >= 1; st >>= 1) {
      int probe = b + st;
      if (probe < 32 && (int)cb[probe] <= target) b = probe;
    }
    uint8_t* lr = &lutb[dim * LUT_BSTRIDE];
    for (int cc = 0; cc < 32; ++cc) {
      int c = target + cc;
      while (b < 31 && (int)cb[b + 1] <= c) ++b;
      lr[c] = (uint8_t)b;
    }
  }
  __syncthreads();

  // ---------------- main loop: 4 dims/lane, float4 I/O ----------------
  int lane = tid & 63;
  int wid = tid >> 6;
  int dq = lane & 3;           // which dim-quad (dims 4*dq .. 4*dq+3)
  int rsub = lane >> 2;        // row within wave (0..15)
  int dml0 = dq * 4;           // local dim base

  int row0 = group * 512 + wid * 16 + rsub;
  size_t base = (size_t)row0 * D_DIM + d0 + dml0;
  float* parts = part + (size_t)slice * B;
  const size_t ISTEP = (size_t)128 * D_DIM;   // 128 rows per block-iter

  float4 xv = *reinterpret_cast<const float4*>(x + base);

#pragma unroll
  for (int it = 0; it < 4; ++it) {
    float4 xn;
    if (it < 3) xn = *reinterpret_cast<const float4*>(x + base + (size_t)(it + 1) * ISTEP);

    float u0, u1, u2, u3, l0, l1, l2, l3;
    eval1(xv.x, dml0 + 0, lentA, lentB, lic, lutb, u0, l0);
    eval1(xv.y, dml0 + 1, lentA, lentB, lic, lutb, u1, l1);
    eval1(xv.z, dml0 + 2, lentA, lentB, lic, lutb, u2, l2);
    eval1(xv.w, dml0 + 3, lentA, lentB, lic, lutb, u3, l3);

    float4 uv = make_float4(u0, u1, u2, u3);
    *reinterpret_cast<float4*>(uout + base + (size_t)it * ISTEP) = uv;

    float ls = (l0 + l1) + (l2 + l3);
    ls = dpp_quadsum4(ls);                 // all 4 lanes of the quad hold the sum
    if (dq == 0) parts[row0 + it * 128] = ls;

    xv = xn;
  }
}

// 128 blocks x 256 threads: ldout[row] = ln2 * sum_s part[s][row]
__global__ void spline_reduce(const float* __restrict__ part,
                              float* __restrict__ ldout, int B) {
  int row = blockIdx.x * 256 + threadIdx.x;
  if (row >= B) return;
  float s = 0.0f;
#pragma unroll
  for (int sl = 0; sl < D_DIM / SLICE; ++sl) s += part[(size_t)sl * B + row];
  ldout[row] = s * LN2_;
}

extern "C" void kernel_launch(void* const* d_in, const int* in_sizes, int n_in,
                              void* d_out, int out_size, void* d_ws, size_t ws_size,
                              hipStream_t stream) {
  const float* x  = (const float*)d_in[0];
  const float* uw = (const float*)d_in[1];
  const float* uh = (const float*)d_in[2];
  const float* ud = (const float*)d_in[3];
  const float* ul = (const float*)d_in[4];

  int B = in_sizes[0] / D_DIM;  // 32768

  float* out = (float*)d_out;
  float* uout = out;
  float* ldout = out + (size_t)B * D_DIM;

  float* partw = (float*)d_ws;  // 16 * B * 4 = 2 MB

  spline_fused<<<1024, 512, 0, stream>>>(x, uw, uh, ud, ul, uout, partw, B);
  spline_reduce<<<(B + 255) / 256, 256, 0, stream>>>(partw, ldout, B);
}

// Round 14
// 30.727 us; speedup vs baseline: 1.1252x; 1.1252x over previous
//
#include <hip/hip_runtime.h>
#include <hip/hip_fp16.h>
#include <math.h>
#include <stdint.h>

#define D_DIM 256
#define K_BINS 32
#define NCELL 1024           // cell 0.00586 < min bin 0.006 -> <=1 boundary/cell
#define ENT4_STRIDE 132      // dwords per dim per half-entry array (32*4 + 4 pad)
#define LIC_STRIDE 34        // floats per dim (33 used + 1 pad)
#define LUT_BSTRIDE 1028     // bytes per dim (1024 + 4 pad)
#define SLICE 16             // dims per block

// slice image layout (dwords): lentA[16*132]=2112 | lentB 2112 | lic 16*34=544 | lut 16*257=4112
#define IMG_A 0
#define IMG_B 2112
#define IMG_LIC 4224
#define IMG_LUT 4768
#define IMG_DW 8880          // 35520 B per slice

static constexpr float BOUND = 3.0f;
static constexpr float MIN_BIN_W = 1e-3f;
static constexpr float MIN_DERIV = 1e-3f;
static constexpr float MIN_LAMBDA = 0.025f;
static constexpr float EPS_ = 1e-6f;
static constexpr float CELL_W = 6.0f / NCELL;
static constexpr float CELL_S = NCELL / 6.0f;
static constexpr float LN2_ = 0.69314718055994531f;

__device__ __forceinline__ float softplusf_(float x) {
  return fmaxf(x, 0.0f) + log1pf(expf(-fabsf(x)));
}

__device__ __forceinline__ float pack2h_as_f32(float a, float b) {
  __half2 h = __halves2half2(__float2half_rn(a), __float2half_rn(b));
  union { __half2 h; uint32_t u; } c;
  c.h = h;
  return __uint_as_float(c.u);
}

__device__ __forceinline__ float2 unpack2h_from_f32(float v) {
  union { uint32_t u; __half2 h; } c;
  c.u = __float_as_uint(v);
  return make_float2(__low2float(c.h), __high2float(c.h));
}

// butterfly sum within each 4-lane quad via DPP quad_perm (VALU pipe)
__device__ __forceinline__ float dpp_quadsum4(float v) {
  int t;
  t = __builtin_amdgcn_update_dpp(0, __float_as_int(v), 0xB1, 0xF, 0xF, false); // xor1
  v += __int_as_float(t);
  t = __builtin_amdgcn_update_dpp(0, __float_as_int(v), 0x4E, 0xF, 0xF, false); // xor2
  v += __int_as_float(t);
  return v;
}

// ---------------- precompute: build math (R12-verbatim) -> global slice images ----------------
// 32 blocks x 256 threads; block owns 8 dims (one (d,k) per thread).
__global__ void spline_precompute(const float* __restrict__ uw,
                                  const float* __restrict__ uh,
                                  const float* __restrict__ ud,
                                  const float* __restrict__ ul,
                                  float* __restrict__ img) {
  __shared__ uint8_t lut8[8 * LUT_BSTRIDE];   // 8224 B

  int tid = threadIdx.x;
  int k = tid & 31;
  int dsub = tid >> 5;           // 0..7
  int d = blockIdx.x * 8 + dsub;
  int s = d >> 4;
  int ds = d & 15;
  float* im = img + (size_t)s * IMG_DW;

  float uwv = uw[d * K_BINS + k];
  float uhv = uh[d * K_BINS + k];
  float ulv = ul[d * K_BINS + k];
  float udv = (k < K_BINS - 1) ? ud[d * (K_BINS - 1) + k] : 0.0f;

  float wm = uwv, hm = uhv;
  for (int o = 16; o; o >>= 1) {
    wm = fmaxf(wm, __shfl_xor(wm, o, 32));
    hm = fmaxf(hm, __shfl_xor(hm, o, 32));
  }
  float ew = expf(uwv - wm), eh = expf(uhv - hm);
  float ws = ew, hs = eh;
  for (int o = 16; o; o >>= 1) {
    ws += __shfl_xor(ws, o, 32);
    hs += __shfl_xor(hs, o, 32);
  }
  const float kfac = 1.0f - MIN_BIN_W * (float)K_BINS;
  float sw = MIN_BIN_W + kfac * (ew / ws);
  float sh = MIN_BIN_W + kfac * (eh / hs);

  float cws = sw, chs = sh;
  for (int o = 1; o < 32; o <<= 1) {
    float tw = __shfl_up(cws, o, 32);
    float th = __shfl_up(chs, o, 32);
    if (k >= o) { cws += tw; chs += th; }
  }
  const float scale = 2.0f * BOUND;
  float raw_w = scale * cws - BOUND;
  float raw_h = scale * chs - BOUND;
  float upw = __shfl_up(raw_w, 1, 32);
  float uph = __shfl_up(raw_h, 1, 32);
  float cw_lo = (k == 0) ? -BOUND : upw;
  float ch_lo = (k == 0) ? -BOUND : uph;
  float cw_hi = (k == K_BINS - 1) ? BOUND : raw_w;
  float ch_hi = (k == K_BINS - 1) ? BOUND : raw_h;

  float iw = cw_hi - cw_lo;
  float ih = ch_hi - ch_lo;

  float dk = MIN_DERIV + softplusf_(udv);
  float dprev = __shfl_up(dk, 1, 32);
  float d1 = (k == K_BINS - 1) ? 1.0f : dk;
  float dd0 = (k == 0) ? 1.0f : dprev;

  float sg = 1.0f / (1.0f + expf(-ulv));
  float lam = MIN_LAMBDA + (1.0f - 2.0f * MIN_LAMBDA) * sg;

  float wb = sqrtf(dd0 / d1);
  float delta = ih / iw;
  float wc = (lam * dd0 + (1.0f - lam) * wb * d1) / delta;
  float denom = (1.0f - lam) + lam * wb;
  float dyc = lam * wb * ih / denom;   // yc - ya
  float dyb = ih - dyc;                // yb - yc
  float ya = ch_lo;
  float inv_iw = 1.0f / iw;
  float yc = ya + dyc;

  float* eA = im + IMG_A + ds * ENT4_STRIDE + k * 4;
  eA[0] = cw_lo;
  eA[1] = inv_iw;
  eA[2] = lam;
  eA[3] = wc;
  float* eB = im + IMG_B + ds * ENT4_STRIDE + k * 4;
  eB[0] = wb;
  eB[1] = yc;
  eB[2] = pack2h_as_f32(dyc, dyb);
  eB[3] = pack2h_as_f32(log2f(wc * lam * dyc * inv_iw),
                        log2f(wc * wb * (1.0f - lam) * dyb * inv_iw));

  float t = cw_lo + EPS_;
  im[IMG_LIC + ds * LIC_STRIDE + k] = t;
  if (k == 0) im[IMG_LIC + ds * LIC_STRIDE + 32] = 1e30f;  // sentinel

  // exact c0 = min{c : cellL(c) >= t}, cellL(c) = fma(c,CELL_W,-3) - 1e-5
  int c0 = 0;
  if (k > 0) {
    float q = (t + BOUND + 1e-5f) * CELL_S;
    c0 = (int)ceilf(q);
    if (c0 < 0) c0 = 0;
    if (c0 > NCELL) c0 = NCELL;
    while (c0 < NCELL && (fmaf((float)c0, CELL_W, -BOUND) - 1e-5f) < t) ++c0;
    while (c0 > 0 && (fmaf((float)(c0 - 1), CELL_W, -BOUND) - 1e-5f) >= t) --c0;
  }
  int c1 = __shfl_down(c0, 1, 32);
  if (k == K_BINS - 1) c1 = NCELL;

  // word-packed scatter into LDS LUT (head bytes / dword body / tail bytes)
  {
    uint8_t* lr = &lut8[dsub * LUT_BSTRIDE];
    int c = c0;
    while (c < c1 && (c & 3)) { lr[c] = (uint8_t)k; ++c; }
    uint32_t kw = (uint32_t)k * 0x01010101u;
    for (; c + 4 <= c1; c += 4) *reinterpret_cast<uint32_t*>(&lr[c]) = kw;
    while (c < c1) { lr[c] = (uint8_t)k; ++c; }
  }
  __syncthreads();

  // coalesced copy LDS LUT -> image (block's 8 dims start at ds0 in slice)
  {
    const uint32_t* l32 = reinterpret_cast<const uint32_t*>(lut8);
    int ds0 = (blockIdx.x & 1) * 8;
    uint32_t* dst = reinterpret_cast<uint32_t*>(im + IMG_LUT) + ds0 * (LUT_BSTRIDE / 4);
    for (int i = tid; i < 8 * (LUT_BSTRIDE / 4); i += 256) dst[i] = l32[i];
  }
}

// one spline eval for local dim `dml` (0..15) from split LDS tables (R12-verbatim)
__device__ __forceinline__ void eval1(
    float xv, int dml,
    const float* lentA, const float* lentB,
    const float* lic, const uint8_t* lutb,
    float& uu_out, float& lad2_out) {
  float xc = fminf(fmaxf(xv, -BOUND), BOUND);
  bool inside = fabsf(xv) <= BOUND;

  float cf = fmaf(xc, CELL_S, (float)(NCELL / 2));
  int c = (int)cf;
  c = min(c, NCELL - 1);
  int ilut = (int)lutb[dml * LUT_BSTRIDE + c];

  float c1 = lic[dml * LIC_STRIDE + ilut + 1];
  int idx = ilut + (xc >= c1 ? 1 : 0);

  int eb = dml * ENT4_STRIDE + idx * 4;
  float4 A = *reinterpret_cast<const float4*>(&lentA[eb]);  // icw,inv_iw,il,wc
  float4 Bv = *reinterpret_cast<const float4*>(&lentB[eb]); // wb,yc,dycdyb,LL

  float icw = A.x, inv_iw = A.y, il = A.z, wcv = A.w;
  float wbv = Bv.x, yc = Bv.y;
  float2 dd = unpack2h_from_f32(Bv.z);   // dyc, dyb
  float2 LL = unpack2h_from_f32(Bv.w);   // Llo, Lhi

  float theta = (xc - icw) * inv_iw;
  bool lo = theta <= il;
  float t1 = il - theta;
  float t3 = 1.0f - theta;

  float den = lo ? fmaf(wcv, theta, t1)
                 : fmaf(wcv, t3, -(wbv * t1));
  float sfac = lo ? dd.x : (wbv * dd.y);
  float Ls = lo ? LL.x : LL.y;

  float r = __builtin_amdgcn_rcpf(den);
  float uu = fmaf(-t1 * sfac, r, yc);
  float lad2 = fmaf(-2.0f, __builtin_amdgcn_logf(den), Ls);  // log2 units

  uu_out = inside ? uu : xv;
  lad2_out = inside ? lad2 : 0.0f;
}

// Fused eval: 1024 blocks x 512 threads (8 waves). Block owns 16 dims
// (slice=blk&15); stages the prebuilt slice image into LDS (float4 memcpy),
// then evaluates 4 dims/lane via float4 I/O (R12 main loop verbatim).
__global__ __launch_bounds__(512) void spline_main(
    const float* __restrict__ x,
    const float* __restrict__ img,
    float* __restrict__ uout,
    float* __restrict__ part,
    int B) {
  __shared__ __align__(16) float ldsflat[IMG_DW];   // 35520 B

  int tid = threadIdx.x;
  int slice = blockIdx.x & 15;
  int group = blockIdx.x >> 4;   // 0..63
  int d0 = slice * SLICE;

  // stage: 2220 float4s
  {
    const float4* s4 = reinterpret_cast<const float4*>(img + (size_t)slice * IMG_DW);
    float4* t4 = reinterpret_cast<float4*>(ldsflat);
    for (int i = tid; i < IMG_DW / 4; i += 512) t4[i] = s4[i];
  }
  __syncthreads();

  const float* lentA = ldsflat + IMG_A;
  const float* lentB = ldsflat + IMG_B;
  const float* lic   = ldsflat + IMG_LIC;
  const uint8_t* lutb = reinterpret_cast<const uint8_t*>(ldsflat + IMG_LUT);

  int lane = tid & 63;
  int wid = tid >> 6;
  int dq = lane & 3;           // which dim-quad (dims 4*dq .. 4*dq+3)
  int rsub = lane >> 2;        // row within wave (0..15)
  int dml0 = dq * 4;           // local dim base

  int row0 = group * 512 + wid * 16 + rsub;
  size_t base = (size_t)row0 * D_DIM + d0 + dml0;
  float* parts = part + (size_t)slice * B;
  const size_t ISTEP = (size_t)128 * D_DIM;   // 128 rows per block-iter

  float4 xv = *reinterpret_cast<const float4*>(x + base);

#pragma unroll
  for (int it = 0; it < 4; ++it) {
    float4 xn;
    if (it < 3) xn = *reinterpret_cast<const float4*>(x + base + (size_t)(it + 1) * ISTEP);

    float u0, u1, u2, u3, l0, l1, l2, l3;
    eval1(xv.x, dml0 + 0, lentA, lentB, lic, lutb, u0, l0);
    eval1(xv.y, dml0 + 1, lentA, lentB, lic, lutb, u1, l1);
    eval1(xv.z, dml0 + 2, lentA, lentB, lic, lutb, u2, l2);
    eval1(xv.w, dml0 + 3, lentA, lentB, lic, lutb, u3, l3);

    float4 uv = make_float4(u0, u1, u2, u3);
    *reinterpret_cast<float4*>(uout + base + (size_t)it * ISTEP) = uv;

    float ls = (l0 + l1) + (l2 + l3);
    ls = dpp_quadsum4(ls);                 // all 4 lanes of the quad hold the sum
    if (dq == 0) parts[row0 + it * 128] = ls;

    xv = xn;
  }
}

// 128 blocks x 256 threads: ldout[row] = ln2 * sum_s part[s][row]
__global__ void spline_reduce(const float* __restrict__ part,
                              float* __restrict__ ldout, int B) {
  int row = blockIdx.x * 256 + threadIdx.x;
  if (row >= B) return;
  float s = 0.0f;
#pragma unroll
  for (int sl = 0; sl < D_DIM / SLICE; ++sl) s += part[(size_t)sl * B + row];
  ldout[row] = s * LN2_;
}

extern "C" void kernel_launch(void* const* d_in, const int* in_sizes, int n_in,
                              void* d_out, int out_size, void* d_ws, size_t ws_size,
                              hipStream_t stream) {
  const float* x  = (const float*)d_in[0];
  const float* uw = (const float*)d_in[1];
  const float* uh = (const float*)d_in[2];
  const float* ud = (const float*)d_in[3];
  const float* ul = (const float*)d_in[4];

  int B = in_sizes[0] / D_DIM;  // 32768

  float* out = (float*)d_out;
  float* uout = out;
  float* ldout = out + (size_t)B * D_DIM;

  float* img = (float*)d_ws;                            // 16*35520 B = 568320 B
  float* partw = (float*)((char*)d_ws + 16 * IMG_DW * 4); // 2 MB

  spline_precompute<<<32, 256, 0, stream>>>(uw, uh, ud, ul, img);
  spline_main<<<1024, 512, 0, stream>>>(x, img, uout, partw, B);
  spline_reduce<<<(B + 255) / 256, 256, 0, stream>>>(partw, ldout, B);
}

// Round 15
// 28.869 us; speedup vs baseline: 1.1976x; 1.0644x over previous
//
#include <hip/hip_runtime.h>
#include <hip/hip_fp16.h>
#include <math.h>
#include <stdint.h>

#define D_DIM 256
#define K_BINS 32
#define NCELL 1024           // cell 0.00586 < min bin 0.006 -> <=1 boundary/cell
#define ENT4_STRIDE 132      // dwords per dim per half-entry array (32*4 + 4 pad)
#define LIC_STRIDE 34        // floats per dim (33 used + 1 pad)
#define LUT_BSTRIDE 1028     // bytes per dim (1024 + 4 pad)
#define SLICE 16             // dims per block

static constexpr float BOUND = 3.0f;
static constexpr float MIN_BIN_W = 1e-3f;
static constexpr float MIN_DERIV = 1e-3f;
static constexpr float MIN_LAMBDA = 0.025f;
static constexpr float EPS_ = 1e-6f;
static constexpr float CELL_W = 6.0f / NCELL;
static constexpr float CELL_S = NCELL / 6.0f;
static constexpr float LN2_ = 0.69314718055994531f;

__device__ __forceinline__ float softplusf_(float x) {
  return fmaxf(x, 0.0f) + log1pf(expf(-fabsf(x)));
}

__device__ __forceinline__ float pack2h_as_f32(float a, float b) {
  __half2 h = __halves2half2(__float2half_rn(a), __float2half_rn(b));
  union { __half2 h; uint32_t u; } c;
  c.h = h;
  return __uint_as_float(c.u);
}

__device__ __forceinline__ float2 unpack2h_from_f32(float v) {
  union { uint32_t u; __half2 h; } c;
  c.u = __float_as_uint(v);
  return make_float2(__low2float(c.h), __high2float(c.h));
}

// butterfly sum within each 4-lane quad via DPP quad_perm (VALU pipe)
__device__ __forceinline__ float dpp_quadsum4(float v) {
  int t;
  t = __builtin_amdgcn_update_dpp(0, __float_as_int(v), 0xB1, 0xF, 0xF, false); // xor1
  v += __int_as_float(t);
  t = __builtin_amdgcn_update_dpp(0, __float_as_int(v), 0x4E, 0xF, 0xF, false); // xor2
  v += __int_as_float(t);
  return v;
}

// one spline eval for local dim `dml` (0..15); returns u, den (1 if outside),
// Ls (0 if outside). Caller does one log per 4 evals on the den product.
__device__ __forceinline__ void eval1(
    float xv, int dml,
    const float* lentA, const float* lentB,
    const float* lic, const uint8_t* lutb,
    float& uu_out, float& den_out, float& Ls_out) {
  float xc = fminf(fmaxf(xv, -BOUND), BOUND);
  bool inside = fabsf(xv) <= BOUND;

  float cf = fmaf(xc, CELL_S, (float)(NCELL / 2));
  int c = (int)cf;
  c = min(c, NCELL - 1);
  int ilut = (int)lutb[dml * LUT_BSTRIDE + c];

  float c1 = lic[dml * LIC_STRIDE + ilut + 1];
  int idx = ilut + (xc >= c1 ? 1 : 0);

  int eb = dml * ENT4_STRIDE + idx * 4;
  float4 A = *reinterpret_cast<const float4*>(&lentA[eb]);  // icw,inv_iw,il,wc
  float4 Bv = *reinterpret_cast<const float4*>(&lentB[eb]); // wb,yc,dycdyb,LL

  float icw = A.x, inv_iw = A.y, il = A.z, wcv = A.w;
  float wbv = Bv.x, yc = Bv.y;
  float2 dd = unpack2h_from_f32(Bv.z);   // dyc, dyb
  float2 LL = unpack2h_from_f32(Bv.w);   // Llo, Lhi

  float theta = (xc - icw) * inv_iw;
  bool lo = theta <= il;
  float t1 = il - theta;
  float t3 = 1.0f - theta;

  float den = lo ? fmaf(wcv, theta, t1)
                 : fmaf(wcv, t3, -(wbv * t1));
  float sfac = lo ? dd.x : (wbv * dd.y);
  float Ls = lo ? LL.x : LL.y;

  float r = __builtin_amdgcn_rcpf(den);
  float uu = fmaf(-t1 * sfac, r, yc);

  uu_out = inside ? uu : xv;
  den_out = inside ? den : 1.0f;
  Ls_out = inside ? Ls : 0.0f;
}

// Fused: 1024 blocks x 512 threads (8 waves). Block owns 16 dims (slice=blk&15),
// builds its own LDS table (R12-verbatim build), then evaluates 4 dims/lane
// via float4 I/O with uniform-base + 32-bit-offset addressing.
__global__ __launch_bounds__(512) void spline_fused(
    const float* __restrict__ x,
    const float* __restrict__ uw,
    const float* __restrict__ uh,
    const float* __restrict__ ud,
    const float* __restrict__ ul,
    float* __restrict__ uout,
    float* __restrict__ part,
    int B) {
  __shared__ __align__(16) float lentA[SLICE * ENT4_STRIDE];  // 8448 B
  __shared__ __align__(16) float lentB[SLICE * ENT4_STRIDE];  // 8448 B
  __shared__ float lic[SLICE * LIC_STRIDE];                   // 2176 B
  __shared__ uint8_t lutb[SLICE * LUT_BSTRIDE];               // 16448 B

  int tid = threadIdx.x;
  int slice = blockIdx.x & 15;
  int group = blockIdx.x >> 4;   // 0..63
  int dbase = slice * SLICE;

  // ---------------- build phase (R12-verbatim) ----------------
  {
    int k = tid & 31;
    int dim = tid >> 5;          // 0..15
    int d = dbase + dim;

    float uwv = uw[d * K_BINS + k];
    float uhv = uh[d * K_BINS + k];
    float ulv = ul[d * K_BINS + k];
    float udv = (k < K_BINS - 1) ? ud[d * (K_BINS - 1) + k] : 0.0f;

    float wm = uwv, hm = uhv;
    for (int o = 16; o; o >>= 1) {
      wm = fmaxf(wm, __shfl_xor(wm, o, 32));
      hm = fmaxf(hm, __shfl_xor(hm, o, 32));
    }
    float ew = expf(uwv - wm), eh = expf(uhv - hm);
    float ws = ew, hs = eh;
    for (int o = 16; o; o >>= 1) {
      ws += __shfl_xor(ws, o, 32);
      hs += __shfl_xor(hs, o, 32);
    }
    const float kfac = 1.0f - MIN_BIN_W * (float)K_BINS;
    float sw = MIN_BIN_W + kfac * (ew / ws);
    float sh = MIN_BIN_W + kfac * (eh / hs);

    float cws = sw, chs = sh;
    for (int o = 1; o < 32; o <<= 1) {
      float tw = __shfl_up(cws, o, 32);
      float th = __shfl_up(chs, o, 32);
      if (k >= o) { cws += tw; chs += th; }
    }
    const float scale = 2.0f * BOUND;
    float raw_w = scale * cws - BOUND;
    float raw_h = scale * chs - BOUND;
    float upw = __shfl_up(raw_w, 1, 32);
    float uph = __shfl_up(raw_h, 1, 32);
    float cw_lo = (k == 0) ? -BOUND : upw;
    float ch_lo = (k == 0) ? -BOUND : uph;
    float cw_hi = (k == K_BINS - 1) ? BOUND : raw_w;
    float ch_hi = (k == K_BINS - 1) ? BOUND : raw_h;

    float iw = cw_hi - cw_lo;
    float ih = ch_hi - ch_lo;

    float dk = MIN_DERIV + softplusf_(udv);
    float dprev = __shfl_up(dk, 1, 32);
    float d1 = (k == K_BINS - 1) ? 1.0f : dk;
    float dd0 = (k == 0) ? 1.0f : dprev;

    float sg = 1.0f / (1.0f + expf(-ulv));
    float lam = MIN_LAMBDA + (1.0f - 2.0f * MIN_LAMBDA) * sg;

    float wb = sqrtf(dd0 / d1);
    float delta = ih / iw;
    float wc = (lam * dd0 + (1.0f - lam) * wb * d1) / delta;
    float denom = (1.0f - lam) + lam * wb;
    float dyc = lam * wb * ih / denom;   // yc - ya
    float dyb = ih - dyc;                // yb - yc
    float ya = ch_lo;
    float inv_iw = 1.0f / iw;
    float yc = ya + dyc;

    float* eA = &lentA[dim * ENT4_STRIDE + k * 4];
    eA[0] = cw_lo;
    eA[1] = inv_iw;
    eA[2] = lam;
    eA[3] = wc;
    float* eB = &lentB[dim * ENT4_STRIDE + k * 4];
    eB[0] = wb;
    eB[1] = yc;
    eB[2] = pack2h_as_f32(dyc, dyb);
    eB[3] = pack2h_as_f32(log2f(wc * lam * dyc * inv_iw),
                          log2f(wc * wb * (1.0f - lam) * dyb * inv_iw));

    float t = cw_lo + EPS_;
    lic[dim * LIC_STRIDE + k] = t;
    if (k == 0) lic[dim * LIC_STRIDE + 32] = 1e30f;  // sentinel

    int c0 = 0;
    if (k > 0) {
      float q = (t + BOUND + 1e-5f) * CELL_S;
      c0 = (int)ceilf(q);
      if (c0 < 0) c0 = 0;
      if (c0 > NCELL) c0 = NCELL;
      while (c0 < NCELL && (fmaf((float)c0, CELL_W, -BOUND) - 1e-5f) < t) ++c0;
      while (c0 > 0 && (fmaf((float)(c0 - 1), CELL_W, -BOUND) - 1e-5f) >= t) --c0;
    }
    int c1 = __shfl_down(c0, 1, 32);
    if (k == K_BINS - 1) c1 = NCELL;
    for (int c = c0; c < c1; ++c) lutb[dim * LUT_BSTRIDE + c] = (uint8_t)k;
  }
  __syncthreads();

  // ---------------- main loop: 4 dims/lane, float4 I/O ----------------
  int lane = tid & 63;
  int wid = tid >> 6;
  int dq = lane & 3;           // which dim-quad (dims 4*dq .. 4*dq+3)
  int rsub = lane >> 2;        // row within wave (0..15)
  int dml0 = dq * 4;           // local dim base

  int row0 = group * 512 + wid * 16 + rsub;
  unsigned off = (unsigned)row0 * D_DIM + dbase + dml0;  // 32-bit lane offset
  float* parts = part + (size_t)slice * B;
  const size_t ISTEP = (size_t)128 * D_DIM;   // 128 rows per block-iter

#pragma unroll
  for (int it = 0; it < 4; ++it) {
    const float* xp = x + (size_t)it * ISTEP;      // uniform base (SGPR)
    float4 xv = *reinterpret_cast<const float4*>(xp + off);

    float u0, u1, u2, u3, dn0, dn1, dn2, dn3, L0, L1, L2, L3;
    eval1(xv.x, dml0 + 0, lentA, lentB, lic, lutb, u0, dn0, L0);
    eval1(xv.y, dml0 + 1, lentA, lentB, lic, lutb, u1, dn1, L1);
    eval1(xv.z, dml0 + 2, lentA, lentB, lic, lutb, u2, dn2, L2);
    eval1(xv.w, dml0 + 3, lentA, lentB, lic, lutb, u3, dn3, L3);

    float* up = uout + (size_t)it * ISTEP;         // uniform base (SGPR)
    *reinterpret_cast<float4*>(up + off) = make_float4(u0, u1, u2, u3);

    // one log per 4 evals: ls = sum(Ls) - 2*log2(prod den)
    float P = (dn0 * dn1) * (dn2 * dn3);
    float Lsum = (L0 + L1) + (L2 + L3);
    float ls = fmaf(-2.0f, __builtin_amdgcn_logf(P), Lsum);  // log2 units

    ls = dpp_quadsum4(ls);                 // all 4 lanes of the quad hold the sum
    if (dq == 0) parts[row0 + it * 128] = ls;
  }
}

// 128 blocks x 256 threads: ldout[row] = ln2 * sum_s part[s][row]
__global__ void spline_reduce(const float* __restrict__ part,
                              float* __restrict__ ldout, int B) {
  int row = blockIdx.x * 256 + threadIdx.x;
  if (row >= B) return;
  float s = 0.0f;
#pragma unroll
  for (int sl = 0; sl < D_DIM / SLICE; ++sl) s += part[(size_t)sl * B + row];
  ldout[row] = s * LN2_;
}

extern "C" void kernel_launch(void* const* d_in, const int* in_sizes, int n_in,
                              void* d_out, int out_size, void* d_ws, size_t ws_size,
                              hipStream_t stream) {
  const float* x  = (const float*)d_in[0];
  const float* uw = (const float*)d_in[1];
  const float* uh = (const float*)d_in[2];
  const float* ud = (const float*)d_in[3];
  const float* ul = (const float*)d_in[4];

  int B = in_sizes[0] / D_DIM;  // 32768

  float* out = (float*)d_out;
  float* uout = out;
  float* ldout = out + (size_t)B * D_DIM;

  float* partw = (float*)d_ws;  // 16 * B * 4 = 2 MB

  spline_fused<<<1024, 512, 0, stream>>>(x, uw, uh, ud, ul, uout, partw, B);
  spline_reduce<<<(B + 255) / 256, 256, 0, stream>>>(partw, ldout, B);
}

// Round 16
// 28.011 us; speedup vs baseline: 1.2343x; 1.0307x over previous
//
#include <hip/hip_runtime.h>
#include <hip/hip_fp16.h>
#include <math.h>
#include <stdint.h>

#define D_DIM 256
#define K_BINS 32
#define NCELL 1024           // cell 0.00586 < min bin 0.006 -> <=1 boundary/cell
#define ENT4_STRIDE 132      // dwords per dim per half-entry array (32*4 + 4 pad)
#define LIC_STRIDE 34        // floats per dim (33 used + 1 pad)
#define LUT_BSTRIDE 1028     // bytes per dim (1024 + 4 pad)
#define SLICE 16             // dims per block

static constexpr float BOUND = 3.0f;
static constexpr float MIN_BIN_W = 1e-3f;
static constexpr float MIN_DERIV = 1e-3f;
static constexpr float MIN_LAMBDA = 0.025f;
static constexpr float EPS_ = 1e-6f;
static constexpr float CELL_W = 6.0f / NCELL;
static constexpr float CELL_S = NCELL / 6.0f;
static constexpr float LN2_ = 0.69314718055994531f;

__device__ __forceinline__ float softplusf_(float x) {
  return fmaxf(x, 0.0f) + log1pf(expf(-fabsf(x)));
}

__device__ __forceinline__ float pack2h_as_f32(float a, float b) {
  __half2 h = __halves2half2(__float2half_rn(a), __float2half_rn(b));
  union { __half2 h; uint32_t u; } c;
  c.h = h;
  return __uint_as_float(c.u);
}

__device__ __forceinline__ float2 unpack2h_from_f32(float v) {
  union { uint32_t u; __half2 h; } c;
  c.u = __float_as_uint(v);
  return make_float2(__low2float(c.h), __high2float(c.h));
}

// butterfly sum within each 4-lane quad via DPP quad_perm (VALU pipe)
__device__ __forceinline__ float dpp_quadsum4(float v) {
  int t;
  t = __builtin_amdgcn_update_dpp(0, __float_as_int(v), 0xB1, 0xF, 0xF, false); // xor1
  v += __int_as_float(t);
  t = __builtin_amdgcn_update_dpp(0, __float_as_int(v), 0x4E, 0xF, 0xF, false); // xor2
  v += __int_as_float(t);
  return v;
}

// one spline eval for local dim `dml` (0..15) from split LDS tables
__device__ __forceinline__ void eval1(
    float xv, int dml,
    const float* lentA, const float* lentB,
    const float* lic, const uint8_t* lutb,
    float& uu_out, float& lad2_out) {
  float xc = fminf(fmaxf(xv, -BOUND), BOUND);
  bool inside = fabsf(xv) <= BOUND;

  float cf = fmaf(xc, CELL_S, (float)(NCELL / 2));
  int c = (int)cf;
  c = min(c, NCELL - 1);
  int ilut = (int)lutb[dml * LUT_BSTRIDE + c];

  float c1 = lic[dml * LIC_STRIDE + ilut + 1];
  int idx = ilut + (xc >= c1 ? 1 : 0);

  int eb = dml * ENT4_STRIDE + idx * 4;
  float4 A = *reinterpret_cast<const float4*>(&lentA[eb]);  // icw,inv_iw,il,wc
  float4 Bv = *reinterpret_cast<const float4*>(&lentB[eb]); // wb,yc,dycdyb,LL

  float icw = A.x, inv_iw = A.y, il = A.z, wcv = A.w;
  float wbv = Bv.x, yc = Bv.y;
  float2 dd = unpack2h_from_f32(Bv.z);   // dyc, dyb
  float2 LL = unpack2h_from_f32(Bv.w);   // Llo, Lhi

  float theta = (xc - icw) * inv_iw;
  bool lo = theta <= il;
  float t1 = il - theta;
  float t3 = 1.0f - theta;

  float den = lo ? fmaf(wcv, theta, t1)
                 : fmaf(wcv, t3, -(wbv * t1));
  float sfac = lo ? dd.x : (wbv * dd.y);
  float Ls = lo ? LL.x : LL.y;

  float r = __builtin_amdgcn_rcpf(den);
  float uu = fmaf(-t1 * sfac, r, yc);
  float lad2 = fmaf(-2.0f, __builtin_amdgcn_logf(den), Ls);  // log2 units

  uu_out = inside ? uu : xv;
  lad2_out = inside ? lad2 : 0.0f;
}

// Fused: 1024 blocks x 512 threads (8 waves). Block owns 16 dims (slice=blk&15),
// builds its own LDS table, then evaluates 4 dims/lane via float4 I/O.
__global__ __launch_bounds__(512) void spline_fused(
    const float* __restrict__ x,
    const float* __restrict__ uw,
    const float* __restrict__ uh,
    const float* __restrict__ ud,
    const float* __restrict__ ul,
    float* __restrict__ uout,
    float* __restrict__ part,
    int B) {
  __shared__ __align__(16) float lentA[SLICE * ENT4_STRIDE];  // 8448 B
  __shared__ __align__(16) float lentB[SLICE * ENT4_STRIDE];  // 8448 B
  __shared__ float lic[SLICE * LIC_STRIDE];                   // 2176 B
  __shared__ uint8_t lutb[SLICE * LUT_BSTRIDE];               // 16448 B

  int tid = threadIdx.x;
  int slice = blockIdx.x & 15;
  int group = blockIdx.x >> 4;   // 0..63
  int d0 = slice * SLICE;

  // ---------------- build phase ----------------
  {
    int k = tid & 31;
    int dim = tid >> 5;          // 0..15
    int d = d0 + dim;

    float uwv = uw[d * K_BINS + k];
    float uhv = uh[d * K_BINS + k];
    float ulv = ul[d * K_BINS + k];
    float udv = (k < K_BINS - 1) ? ud[d * (K_BINS - 1) + k] : 0.0f;

    float wm = uwv, hm = uhv;
    for (int o = 16; o; o >>= 1) {
      wm = fmaxf(wm, __shfl_xor(wm, o, 32));
      hm = fmaxf(hm, __shfl_xor(hm, o, 32));
    }
    float ew = expf(uwv - wm), eh = expf(uhv - hm);
    float ws = ew, hs = eh;
    for (int o = 16; o; o >>= 1) {
      ws += __shfl_xor(ws, o, 32);
      hs += __shfl_xor(hs, o, 32);
    }
    const float kfac = 1.0f - MIN_BIN_W * (float)K_BINS;
    float sw = MIN_BIN_W + kfac * (ew / ws);
    float sh = MIN_BIN_W + kfac * (eh / hs);

    float cws = sw, chs = sh;
    for (int o = 1; o < 32; o <<= 1) {
      float tw = __shfl_up(cws, o, 32);
      float th = __shfl_up(chs, o, 32);
      if (k >= o) { cws += tw; chs += th; }
    }
    const float scale = 2.0f * BOUND;
    float raw_w = scale * cws - BOUND;
    float raw_h = scale * chs - BOUND;
    float upw = __shfl_up(raw_w, 1, 32);
    float uph = __shfl_up(raw_h, 1, 32);
    float cw_lo = (k == 0) ? -BOUND : upw;
    float ch_lo = (k == 0) ? -BOUND : uph;
    float cw_hi = (k == K_BINS - 1) ? BOUND : raw_w;
    float ch_hi = (k == K_BINS - 1) ? BOUND : raw_h;

    float iw = cw_hi - cw_lo;
    float ih = ch_hi - ch_lo;

    float dk = MIN_DERIV + softplusf_(udv);
    float dprev = __shfl_up(dk, 1, 32);
    float d1 = (k == K_BINS - 1) ? 1.0f : dk;
    float dd0 = (k == 0) ? 1.0f : dprev;

    float sg = 1.0f / (1.0f + expf(-ulv));
    float lam = MIN_LAMBDA + (1.0f - 2.0f * MIN_LAMBDA) * sg;

    float wb = sqrtf(dd0 / d1);
    float delta = ih / iw;
    float wc = (lam * dd0 + (1.0f - lam) * wb * d1) / delta;
    float denom = (1.0f - lam) + lam * wb;
    float dyc = lam * wb * ih / denom;   // yc - ya
    float dyb = ih - dyc;                // yb - yc
    float ya = ch_lo;
    float inv_iw = 1.0f / iw;
    float yc = ya + dyc;

    float* eA = &lentA[dim * ENT4_STRIDE + k * 4];
    eA[0] = cw_lo;
    eA[1] = inv_iw;
    eA[2] = lam;
    eA[3] = wc;
    float* eB = &lentB[dim * ENT4_STRIDE + k * 4];
    eB[0] = wb;
    eB[1] = yc;
    eB[2] = pack2h_as_f32(dyc, dyb);
    eB[3] = pack2h_as_f32(log2f(wc * lam * dyc * inv_iw),
                          log2f(wc * wb * (1.0f - lam) * dyb * inv_iw));

    float t = cw_lo + EPS_;
    lic[dim * LIC_STRIDE + k] = t;
    if (k == 0) lic[dim * LIC_STRIDE + 32] = 1e30f;  // sentinel

    int c0 = 0;
    if (k > 0) {
      float q = (t + BOUND + 1e-5f) * CELL_S;
      c0 = (int)ceilf(q);
      if (c0 < 0) c0 = 0;
      if (c0 > NCELL) c0 = NCELL;
      while (c0 < NCELL && (fmaf((float)c0, CELL_W, -BOUND) - 1e-5f) < t) ++c0;
      while (c0 > 0 && (fmaf((float)(c0 - 1), CELL_W, -BOUND) - 1e-5f) >= t) --c0;
    }
    int c1 = __shfl_down(c0, 1, 32);
    if (k == K_BINS - 1) c1 = NCELL;

    // word-packed scatter: head bytes / dword body / tail bytes (~4x fewer iters)
    {
      uint8_t* lr = &lutb[dim * LUT_BSTRIDE];
      int c = c0;
      while (c < c1 && (c & 3)) { lr[c] = (uint8_t)k; ++c; }
      uint32_t kw = (uint32_t)k * 0x01010101u;
      for (; c + 4 <= c1; c += 4) *reinterpret_cast<uint32_t*>(&lr[c]) = kw;
      while (c < c1) { lr[c] = (uint8_t)k; ++c; }
    }
  }
  __syncthreads();

  // ---------------- main loop: 4 dims/lane, float4 I/O ----------------
  int lane = tid & 63;
  int wid = tid >> 6;
  int dq = lane & 3;           // which dim-quad (dims 4*dq .. 4*dq+3)
  int rsub = lane >> 2;        // row within wave (0..15)
  int dml0 = dq * 4;           // local dim base

  int row0 = group * 512 + wid * 16 + rsub;
  size_t base = (size_t)row0 * D_DIM + d0 + dml0;
  float* parts = part + (size_t)slice * B;
  const size_t ISTEP = (size_t)128 * D_DIM;   // 128 rows per block-iter

  float4 xv = *reinterpret_cast<const float4*>(x + base);

#pragma unroll
  for (int it = 0; it < 4; ++it) {
    float4 xn;
    if (it < 3) xn = *reinterpret_cast<const float4*>(x + base + (size_t)(it + 1) * ISTEP);

    float u0, u1, u2, u3, l0, l1, l2, l3;
    eval1(xv.x, dml0 + 0, lentA, lentB, lic, lutb, u0, l0);
    eval1(xv.y, dml0 + 1, lentA, lentB, lic, lutb, u1, l1);
    eval1(xv.z, dml0 + 2, lentA, lentB, lic, lutb, u2, l2);
    eval1(xv.w, dml0 + 3, lentA, lentB, lic, lutb, u3, l3);

    float4 uv = make_float4(u0, u1, u2, u3);
    *reinterpret_cast<float4*>(uout + base + (size_t)it * ISTEP) = uv;

    float ls = (l0 + l1) + (l2 + l3);
    ls = dpp_quadsum4(ls);                 // all 4 lanes of the quad hold the sum
    if (dq == 0) parts[row0 + it * 128] = ls;

    xv = xn;
  }
}

// 128 blocks x 256 threads: ldout[row] = ln2 * sum_s part[s][row]
__global__ void spline_reduce(const float* __restrict__ part,
                              float* __restrict__ ldout, int B) {
  int row = blockIdx.x * 256 + threadIdx.x;
  if (row >= B) return;
  float s = 0.0f;
#pragma unroll
  for (int sl = 0; sl < D_DIM / SLICE; ++sl) s += part[(size_t)sl * B + row];
  ldout[row] = s * LN2_;
}

extern "C" void kernel_launch(void* const* d_in, const int* in_sizes, int n_in,
                              void* d_out, int out_size, void* d_ws, size_t ws_size,
                              hipStream_t stream) {
  const float* x  = (const float*)d_in[0];
  const float* uw = (const float*)d_in[1];
  const float* uh = (const float*)d_in[2];
  const float* ud = (const float*)d_in[3];
  const float* ul = (const float*)d_in[4];

  int B = in_sizes[0] / D_DIM;  // 32768

  float* out = (float*)d_out;
  float* uout = out;
  float* ldout = out + (size_t)B * D_DIM;

  float* partw = (float*)d_ws;  // 16 * B * 4 = 2 MB

  spline_fused<<<1024, 512, 0, stream>>>(x, uw, uh, ud, ul, uout, partw, B);
  spline_reduce<<<(B + 255) / 256, 256, 0, stream>>>(partw, ldout, B);
}

// Round 17
// 27.957 us; speedup vs baseline: 1.2366x; 1.0019x over previous
//
#include <hip/hip_runtime.h>
#include <hip/hip_fp16.h>
#include <math.h>
#include <stdint.h>

#define D_DIM 256
#define K_BINS 32
#define NCELL 1024           // cell 0.00586 < min bin 0.006 -> <=1 boundary/cell
#define ENT4_STRIDE 144      // dwords per dim (32 entries*4 + 3 group pads*4 + 4)
#define LIC_STRIDE 34        // floats per dim (33 used + 1 pad)
#define LUT_BSTRIDE 1028     // bytes per dim (1024 + 4 pad)
#define SLICE 16             // dims per block

static constexpr float BOUND = 3.0f;
static constexpr float MIN_BIN_W = 1e-3f;
static constexpr float MIN_DERIV = 1e-3f;
static constexpr float MIN_LAMBDA = 0.025f;
static constexpr float EPS_ = 1e-6f;
static constexpr float CELL_W = 6.0f / NCELL;
static constexpr float CELL_S = NCELL / 6.0f;
static constexpr float LN2_ = 0.69314718055994531f;

// entry slot for bin idx: 16B-aligned, phase de-clustered across idx mod 8 groups
__device__ __forceinline__ int ent_off(int idx) {
  return (idx + (idx >> 3)) << 2;   // 4*(idx + idx/8)
}

__device__ __forceinline__ float softplusf_(float x) {
  return fmaxf(x, 0.0f) + log1pf(expf(-fabsf(x)));
}

__device__ __forceinline__ float pack2h_as_f32(float a, float b) {
  __half2 h = __halves2half2(__float2half_rn(a), __float2half_rn(b));
  union { __half2 h; uint32_t u; } c;
  c.h = h;
  return __uint_as_float(c.u);
}

__device__ __forceinline__ float2 unpack2h_from_f32(float v) {
  union { uint32_t u; __half2 h; } c;
  c.u = __float_as_uint(v);
  return make_float2(__low2float(c.h), __high2float(c.h));
}

// butterfly sum within each 4-lane quad via DPP quad_perm (VALU pipe)
__device__ __forceinline__ float dpp_quadsum4(float v) {
  int t;
  t = __builtin_amdgcn_update_dpp(0, __float_as_int(v), 0xB1, 0xF, 0xF, false); // xor1
  v += __int_as_float(t);
  t = __builtin_amdgcn_update_dpp(0, __float_as_int(v), 0x4E, 0xF, 0xF, false); // xor2
  v += __int_as_float(t);
  return v;
}

// one spline eval for local dim `dml` (0..15) from split LDS tables
__device__ __forceinline__ void eval1(
    float xv, int dml,
    const float* lentA, const float* lentB,
    const float* lic, const uint8_t* lutb,
    float& uu_out, float& lad2_out) {
  float xc = fminf(fmaxf(xv, -BOUND), BOUND);
  bool inside = fabsf(xv) <= BOUND;

  float cf = fmaf(xc, CELL_S, (float)(NCELL / 2));
  int c = (int)cf;
  c = min(c, NCELL - 1);
  int ilut = (int)lutb[dml * LUT_BSTRIDE + c];

  float c1 = lic[dml * LIC_STRIDE + ilut + 1];
  int idx = ilut + (xc >= c1 ? 1 : 0);

  int eb = dml * ENT4_STRIDE + ent_off(idx);
  float4 A = *reinterpret_cast<const float4*>(&lentA[eb]);  // icw,inv_iw,il,wc
  float4 Bv = *reinterpret_cast<const float4*>(&lentB[eb]); // wb,yc,dycdyb,LL

  float icw = A.x, inv_iw = A.y, il = A.z, wcv = A.w;
  float wbv = Bv.x, yc = Bv.y;
  float2 dd = unpack2h_from_f32(Bv.z);   // dyc, dyb
  float2 LL = unpack2h_from_f32(Bv.w);   // Llo, Lhi

  float theta = (xc - icw) * inv_iw;
  bool lo = theta <= il;
  float t1 = il - theta;
  float t3 = 1.0f - theta;

  float den = lo ? fmaf(wcv, theta, t1)
                 : fmaf(wcv, t3, -(wbv * t1));
  float sfac = lo ? dd.x : (wbv * dd.y);
  float Ls = lo ? LL.x : LL.y;

  float r = __builtin_amdgcn_rcpf(den);
  float uu = fmaf(-t1 * sfac, r, yc);
  float lad2 = fmaf(-2.0f, __builtin_amdgcn_logf(den), Ls);  // log2 units

  uu_out = inside ? uu : xv;
  lad2_out = inside ? lad2 : 0.0f;
}

// Fused: 1024 blocks x 512 threads (8 waves). Block owns 16 dims (slice=blk&15),
// builds its own LDS table, then evaluates 4 dims/lane via float4 I/O.
__global__ __launch_bounds__(512) void spline_fused(
    const float* __restrict__ x,
    const float* __restrict__ uw,
    const float* __restrict__ uh,
    const float* __restrict__ ud,
    const float* __restrict__ ul,
    float* __restrict__ uout,
    float* __restrict__ part,
    int B) {
  __shared__ __align__(16) float lentA[SLICE * ENT4_STRIDE];  // 9216 B
  __shared__ __align__(16) float lentB[SLICE * ENT4_STRIDE];  // 9216 B
  __shared__ float lic[SLICE * LIC_STRIDE];                   // 2176 B
  __shared__ uint8_t lutb[SLICE * LUT_BSTRIDE];               // 16448 B

  int tid = threadIdx.x;
  int slice = blockIdx.x & 15;
  int group = blockIdx.x >> 4;   // 0..63
  int d0 = slice * SLICE;

  // ---------------- build phase ----------------
  {
    int k = tid & 31;
    int dim = tid >> 5;          // 0..15
    int d = d0 + dim;

    float uwv = uw[d * K_BINS + k];
    float uhv = uh[d * K_BINS + k];
    float ulv = ul[d * K_BINS + k];
    float udv = (k < K_BINS - 1) ? ud[d * (K_BINS - 1) + k] : 0.0f;

    float wm = uwv, hm = uhv;
    for (int o = 16; o; o >>= 1) {
      wm = fmaxf(wm, __shfl_xor(wm, o, 32));
      hm = fmaxf(hm, __shfl_xor(hm, o, 32));
    }
    float ew = expf(uwv - wm), eh = expf(uhv - hm);
    float ws = ew, hs = eh;
    for (int o = 16; o; o >>= 1) {
      ws += __shfl_xor(ws, o, 32);
      hs += __shfl_xor(hs, o, 32);
    }
    const float kfac = 1.0f - MIN_BIN_W * (float)K_BINS;
    float sw = MIN_BIN_W + kfac * (ew / ws);
    float sh = MIN_BIN_W + kfac * (eh / hs);

    float cws = sw, chs = sh;
    for (int o = 1; o < 32; o <<= 1) {
      float tw = __shfl_up(cws, o, 32);
      float th = __shfl_up(chs, o, 32);
      if (k >= o) { cws += tw; chs += th; }
    }
    const float scale = 2.0f * BOUND;
    float raw_w = scale * cws - BOUND;
    float raw_h = scale * chs - BOUND;
    float upw = __shfl_up(raw_w, 1, 32);
    float uph = __shfl_up(raw_h, 1, 32);
    float cw_lo = (k == 0) ? -BOUND : upw;
    float ch_lo = (k == 0) ? -BOUND : uph;
    float cw_hi = (k == K_BINS - 1) ? BOUND : raw_w;
    float ch_hi = (k == K_BINS - 1) ? BOUND : raw_h;

    float iw = cw_hi - cw_lo;
    float ih = ch_hi - ch_lo;

    float dk = MIN_DERIV + softplusf_(udv);
    float dprev = __shfl_up(dk, 1, 32);
    float d1 = (k == K_BINS - 1) ? 1.0f : dk;
    float dd0 = (k == 0) ? 1.0f : dprev;

    float sg = 1.0f / (1.0f + expf(-ulv));
    float lam = MIN_LAMBDA + (1.0f - 2.0f * MIN_LAMBDA) * sg;

    float wb = sqrtf(dd0 / d1);
    float delta = ih / iw;
    float wc = (lam * dd0 + (1.0f - lam) * wb * d1) / delta;
    float denom = (1.0f - lam) + lam * wb;
    float dyc = lam * wb * ih / denom;   // yc - ya
    float dyb = ih - dyc;                // yb - yc
    float ya = ch_lo;
    float inv_iw = 1.0f / iw;
    float yc = ya + dyc;

    int eoff = dim * ENT4_STRIDE + ent_off(k);
    float* eA = &lentA[eoff];
    eA[0] = cw_lo;
    eA[1] = inv_iw;
    eA[2] = lam;
    eA[3] = wc;
    float* eB = &lentB[eoff];
    eB[0] = wb;
    eB[1] = yc;
    eB[2] = pack2h_as_f32(dyc, dyb);
    eB[3] = pack2h_as_f32(log2f(wc * lam * dyc * inv_iw),
                          log2f(wc * wb * (1.0f - lam) * dyb * inv_iw));

    float t = cw_lo + EPS_;
    lic[dim * LIC_STRIDE + k] = t;
    if (k == 0) lic[dim * LIC_STRIDE + 32] = 1e30f;  // sentinel

    int c0 = 0;
    if (k > 0) {
      float q = (t + BOUND + 1e-5f) * CELL_S;
      c0 = (int)ceilf(q);
      if (c0 < 0) c0 = 0;
      if (c0 > NCELL) c0 = NCELL;
      while (c0 < NCELL && (fmaf((float)c0, CELL_W, -BOUND) - 1e-5f) < t) ++c0;
      while (c0 > 0 && (fmaf((float)(c0 - 1), CELL_W, -BOUND) - 1e-5f) >= t) --c0;
    }
    int c1 = __shfl_down(c0, 1, 32);
    if (k == K_BINS - 1) c1 = NCELL;

    // word-packed scatter: head bytes / dword body / tail bytes
    {
      uint8_t* lr = &lutb[dim * LUT_BSTRIDE];
      int c = c0;
      while (c < c1 && (c & 3)) { lr[c] = (uint8_t)k; ++c; }
      uint32_t kw = (uint32_t)k * 0x01010101u;
      for (; c + 4 <= c1; c += 4) *reinterpret_cast<uint32_t*>(&lr[c]) = kw;
      while (c < c1) { lr[c] = (uint8_t)k; ++c; }
    }
  }
  __syncthreads();

  // ---------------- main loop: 4 dims/lane, float4 I/O ----------------
  int lane = tid & 63;
  int wid = tid >> 6;
  int dq = lane & 3;           // which dim-quad (dims 4*dq .. 4*dq+3)
  int rsub = lane >> 2;        // row within wave (0..15)
  int dml0 = dq * 4;           // local dim base

  int row0 = group * 512 + wid * 16 + rsub;
  size_t base = (size_t)row0 * D_DIM + d0 + dml0;
  float* parts = part + (size_t)slice * B;
  const size_t ISTEP = (size_t)128 * D_DIM;   // 128 rows per block-iter

  float4 xv = *reinterpret_cast<const float4*>(x + base);

#pragma unroll
  for (int it = 0; it < 4; ++it) {
    float4 xn;
    if (it < 3) xn = *reinterpret_cast<const float4*>(x + base + (size_t)(it + 1) * ISTEP);

    float u0, u1, u2, u3, l0, l1, l2, l3;
    eval1(xv.x, dml0 + 0, lentA, lentB, lic, lutb, u0, l0);
    eval1(xv.y, dml0 + 1, lentA, lentB, lic, lutb, u1, l1);
    eval1(xv.z, dml0 + 2, lentA, lentB, lic, lutb, u2, l2);
    eval1(xv.w, dml0 + 3, lentA, lentB, lic, lutb, u3, l3);

    float4 uv = make_float4(u0, u1, u2, u3);
    *reinterpret_cast<float4*>(uout + base + (size_t)it * ISTEP) = uv;

    float ls = (l0 + l1) + (l2 + l3);
    ls = dpp_quadsum4(ls);                 // all 4 lanes of the quad hold the sum
    if (dq == 0) parts[row0 + it * 128] = ls;

    xv = xn;
  }
}

// 128 blocks x 256 threads: ldout[row] = ln2 * sum_s part[s][row]
__global__ void spline_reduce(const float* __restrict__ part,
                              float* __restrict__ ldout, int B) {
  int row = blockIdx.x * 256 + threadIdx.x;
  if (row >= B) return;
  float s = 0.0f;
#pragma unroll
  for (int sl = 0; sl < D_DIM / SLICE; ++sl) s += part[(size_t)sl * B + row];
  ldout[row] = s * LN2_;
}

extern "C" void kernel_launch(void* const* d_in, const int* in_sizes, int n_in,
                              void* d_out, int out_size, void* d_ws, size_t ws_size,
                              hipStream_t stream) {
  const float* x  = (const float*)d_in[0];
  const float* uw = (const float*)d_in[1];
  const float* uh = (const float*)d_in[2];
  const float* ud = (const float*)d_in[3];
  const float* ul = (const float*)d_in[4];

  int B = in_sizes[0] / D_DIM;  // 32768

  float* out = (float*)d_out;
  float* uout = out;
  float* ldout = out + (size_t)B * D_DIM;

  float* partw = (float*)d_ws;  // 16 * B * 4 = 2 MB

  spline_fused<<<1024, 512, 0, stream>>>(x, uw, uh, ud, ul, uout, partw, B);
  spline_reduce<<<(B + 255) / 256, 256, 0, stream>>>(partw, ldout, B);
}